// Round 1
// baseline (438.863 us; speedup 1.0000x reference)
//
#include <hip/hip_runtime.h>
#include <hip/hip_bf16.h>
#include <math.h>

// Problem constants (from setup_inputs): B=64, way=5, shot=1, D=640, H=W=5 (hw=25), nq=75, k=5
#define NB    64
#define WAY   5
#define DCH   640
#define HW    25
#define NQ    75
#define NBK   5          // neighbor_k
#define EPSN  1e-12f

// ---------------------------------------------------------------------------
// K1: support prep. One block per (b,way). Computes:
//   invs[bk][l] = 1/||base[b,k,:,l]||        (column norms, no eps — matches ref)
//   bm[bk][d]   = mean_l(base[b,k,d,:]) / max(||mean||, eps)
// ---------------------------------------------------------------------------
__global__ __launch_bounds__(256) void k_support(const float* __restrict__ base,
                                                 float* __restrict__ invs,
                                                 float* __restrict__ bm)
{
    const int bk = blockIdx.x;                 // 0..319
    const float* src = base + (size_t)bk * (DCH * HW);
    __shared__ float lds[DCH * HW];            // 64000 B
    __shared__ float lmean[DCH];
    __shared__ float red[256];
    const int tid = threadIdx.x;

    // stage 64KB tile, vectorized
    const float4* src4 = (const float4*)src;
    float4* lds4 = (float4*)lds;
    for (int i = tid; i < (DCH * HW) / 4; i += 256) lds4[i] = src4[i];
    __syncthreads();

    // column L2 norms (25 columns), threads 0..24
    if (tid < HW) {
        float ss = 0.f;
        for (int d = 0; d < DCH; ++d) { float v = lds[d * HW + tid]; ss = fmaf(v, v, ss); }
        invs[bk * HW + tid] = 1.0f / sqrtf(ss);
    }

    // per-d mean over hw + sum of squares of means
    float ssq = 0.f;
    for (int d = tid; d < DCH; d += 256) {
        float s = 0.f;
        #pragma unroll
        for (int p = 0; p < HW; ++p) s += lds[d * HW + p];
        float m = s * (1.0f / HW);
        lmean[d] = m;
        ssq = fmaf(m, m, ssq);
    }
    red[tid] = ssq;
    __syncthreads();
    for (int s = 128; s > 0; s >>= 1) {
        if (tid < s) red[tid] += red[tid + s];
        __syncthreads();
    }
    const float inv = 1.0f / fmaxf(sqrtf(red[0]), EPSN);
    for (int d = tid; d < DCH; d += 256) bm[bk * DCH + d] = lmean[d] * inv;
}

// ---------------------------------------------------------------------------
// K2: global-cosine branch. One block per (b,q). Writes out = r0 * qm·bm.
// (This OVERWRITES d_out; k_dn4 then accumulates into it.)
// ---------------------------------------------------------------------------
__device__ inline float wave_red_sum(float v)
{
    #pragma unroll
    for (int o = 32; o > 0; o >>= 1) v += __shfl_down(v, o);
    return v;
}

__global__ __launch_bounds__(256) void k_global(const float* __restrict__ query,
                                                const float* __restrict__ bm,
                                                const float* __restrict__ r,
                                                float* __restrict__ out)
{
    const int bq = blockIdx.x;                 // 0..4799
    const int b  = bq / NQ;
    const float* src = query + (size_t)bq * (DCH * HW);
    const int tid  = threadIdx.x;
    const int lane = tid & 63;
    const int wid  = tid >> 6;

    // each thread owns d = tid, tid+256, tid+512 (<640)
    float mm[3] = {0.f, 0.f, 0.f};
    float ssq = 0.f;
    #pragma unroll
    for (int j = 0; j < 3; ++j) {
        int d = tid + j * 256;
        if (d < DCH) {
            float s = 0.f;
            #pragma unroll
            for (int p = 0; p < HW; ++p) s += src[d * HW + p];
            mm[j] = s * (1.0f / HW);
            ssq = fmaf(mm[j], mm[j], ssq);
        }
    }

    __shared__ float part[4][8];
    float w = wave_red_sum(ssq);
    if (lane == 0) part[wid][0] = w;

    #pragma unroll
    for (int k = 0; k < WAY; ++k) {
        const float* bmk = bm + (size_t)(b * WAY + k) * DCH;
        float acc = 0.f;
        #pragma unroll
        for (int j = 0; j < 3; ++j) {
            int d = tid + j * 256;
            if (d < DCH) acc = fmaf(mm[j], bmk[d], acc);
        }
        w = wave_red_sum(acc);
        if (lane == 0) part[wid][1 + k] = w;
    }
    __syncthreads();
    if (tid == 0) {
        float ssqT = part[0][0] + part[1][0] + part[2][0] + part[3][0];
        float invq = 1.0f / fmaxf(sqrtf(ssqT), EPSN);
        float r0 = r[0];
        #pragma unroll
        for (int k = 0; k < WAY; ++k) {
            float dot = part[0][1 + k] + part[1][1 + k] + part[2][1 + k] + part[3][1 + k];
            out[(size_t)bq * WAY + k] = r0 * dot * invq;
        }
    }
}

// ---------------------------------------------------------------------------
// K3: DN4 branch. One block per (b, qchunk of 10, k). 256 threads, 250 active:
// thread = one query patch row (q,p); computes 25 raw dots vs support columns
// (support values are block-uniform -> SGPR s_loads; 25 VALU FMA per lane load),
// scales by 1/||qrow|| * invs[l], top-5 per row, LDS-reduce over the 25 rows
// of each query, then out[b,q,k] += r1 * sum / 5.
// ---------------------------------------------------------------------------
__global__ __launch_bounds__(256) void k_dn4(const float* __restrict__ base,
                                             const float* __restrict__ query,
                                             const float* __restrict__ invs,
                                             const float* __restrict__ r,
                                             float* out)
{
    const int blk = blockIdx.x;                // (b*8 + qc)*5 + k  -> k fastest: 5
    const int k  = blk % WAY;                  // consecutive blocks share query rows (L2)
    const int t  = blk / WAY;
    const int qc = t % 8;
    const int b  = t / 8;
    const int tid = threadIdx.x;
    const int ql = tid / HW;
    const int p  = tid - ql * HW;
    const int q  = qc * 10 + ql;
    const bool active = (tid < 250) && (q < NQ);

    float acc[HW];
    #pragma unroll
    for (int l = 0; l < HW; ++l) acc[l] = 0.f;
    float ssq = 0.f;

    const float* s = base + (size_t)(b * WAY + k) * (DCH * HW);   // block-uniform

    if (active) {
        const float* qrow = query + (size_t)(b * NQ + q) * (DCH * HW) + p;
        #pragma unroll 1
        for (int d = 0; d < DCH; d += 2) {
            float q0 = qrow[d * HW];
            float q1 = qrow[d * HW + HW];
            ssq = fmaf(q0, q0, ssq);
            ssq = fmaf(q1, q1, ssq);
            #pragma unroll
            for (int l = 0; l < HW; ++l) acc[l] = fmaf(q0, s[d * HW + l], acc[l]);
            #pragma unroll
            for (int l = 0; l < HW; ++l) acc[l] = fmaf(q1, s[d * HW + HW + l], acc[l]);
        }
    }

    float tot = 0.f;
    if (active) {
        const float invq = rsqrtf(ssq);        // ref divides by exact norm (no eps)
        const float* invs_bk = invs + (b * WAY + k) * HW;
        #pragma unroll
        for (int l = 0; l < HW; ++l) acc[l] *= invq * invs_bk[l];

        // top-5 over the 25 scaled sims, all static register indices
        #pragma unroll
        for (int it = 0; it < NBK; ++it) {
            float m = acc[0];
            #pragma unroll
            for (int l = 1; l < HW; ++l) m = fmaxf(m, acc[l]);
            tot += m;
            bool rem = false;
            #pragma unroll
            for (int l = 0; l < HW; ++l) {
                bool hit = (!rem) && (acc[l] == m);
                acc[l] = hit ? -3.402823466e38f : acc[l];
                rem = rem || hit;
            }
        }
    }

    __shared__ float redv[256];
    redv[tid] = tot;
    __syncthreads();
    if (tid < 10) {
        int qq = qc * 10 + tid;
        if (qq < NQ) {
            float ssum = 0.f;
            #pragma unroll
            for (int pp = 0; pp < HW; ++pp) ssum += redv[tid * HW + pp];
            out[(size_t)((b * NQ + qq) * WAY + k)] += r[1] * ssum * (1.0f / NBK);
        }
    }
}

// ---------------------------------------------------------------------------
extern "C" void kernel_launch(void* const* d_in, const int* in_sizes, int n_in,
                              void* d_out, int out_size, void* d_ws, size_t ws_size,
                              hipStream_t stream)
{
    const float* base  = (const float*)d_in[0];
    const float* query = (const float*)d_in[1];
    const float* r     = (const float*)d_in[2];
    // d_in[3] = neighbor_k (5), compile-time constant here
    float* out = (float*)d_out;

    float* invs = (float*)d_ws;                          // 320*25      = 8000 floats
    float* bm   = invs + NB * WAY * HW;                  // 320*640     = 204800 floats

    k_support<<<NB * WAY, 256, 0, stream>>>(base, invs, bm);
    k_global<<<NB * NQ, 256, 0, stream>>>(query, bm, r, out);
    k_dn4<<<NB * 8 * WAY, 256, 0, stream>>>(base, query, invs, r, out);
}

// Round 2
// 131.894 us; speedup vs baseline: 3.3274x; 3.3274x over previous
//
#include <hip/hip_runtime.h>
#include <hip/hip_bf16.h>
#include <math.h>

// Problem constants: B=64, way=5, shot=1, D=640, H=W=5 (hw=25), nq=75, k=5
#define NB    64
#define WAY   5
#define DCH   640
#define HW    25
#define NQ    75
#define NBK   5
#define EPSN  1e-12f

#define KC    160            // K-chunk staged in LDS
#define NCH   (DCH / KC)     // 4 chunks
#define DG    (KC / 8)       // 20 d-groups per chunk
#define ROWS  129            // 128 support cols + 1 pad row (bank spread)
#define QPB   4              // queries per block = waves per block
#define BPB   ((NQ + QPB - 1) / QPB)   // 19 blocks per b

typedef __attribute__((ext_vector_type(8)))  short bf16x8;
typedef __attribute__((ext_vector_type(16))) float f32x16;

__device__ inline ushort f2bf(float f) {
    uint u = __float_as_uint(f);
    return (ushort)((u + 0x7FFFu + ((u >> 16) & 1u)) >> 16);   // RNE
}

// ---------------------------------------------------------------------------
// K1: per (b,way): column inv-norms invs[bk*25+l] and 1/max(||smean||,eps).
// ---------------------------------------------------------------------------
__global__ __launch_bounds__(256) void k_prep(const float* __restrict__ base,
                                              float* __restrict__ invs,
                                              float* __restrict__ invsm)
{
    const int bk = blockIdx.x;                 // 0..319
    const float* src = base + (size_t)bk * (DCH * HW);
    __shared__ float lds[DCH * HW];
    __shared__ float red[256];
    const int tid = threadIdx.x;

    const float4* s4 = (const float4*)src;
    float4* l4 = (float4*)lds;
    for (int i = tid; i < (DCH * HW) / 4; i += 256) l4[i] = s4[i];
    __syncthreads();

    if (tid < HW) {
        float ss = 0.f;
        for (int d = 0; d < DCH; ++d) { float v = lds[d * HW + tid]; ss = fmaf(v, v, ss); }
        invs[bk * HW + tid] = rsqrtf(ss);      // ref: no eps on column norms
    }

    float ssq = 0.f;
    for (int d = tid; d < DCH; d += 256) {
        float s = 0.f;
        #pragma unroll
        for (int pp = 0; pp < HW; ++pp) s += lds[d * HW + pp];
        float m = s * (1.0f / HW);
        ssq = fmaf(m, m, ssq);
    }
    red[tid] = ssq;
    __syncthreads();
    for (int s = 128; s > 0; s >>= 1) {
        if (tid < s) red[tid] += red[tid + s];
        __syncthreads();
    }
    if (tid == 0) invsm[bk] = 1.0f / fmaxf(sqrtf(red[0]), EPSN);
}

// ---------------------------------------------------------------------------
// K2: fused MFMA kernel. Block = (b, 4 queries), wave = one query.
// A (LDS, bf16): raw support cols, scol = k*25+l in 0..124 (+3 zero rows).
// LDS layout: s_lds[dgroup][scol][8 bf16] so A-frag reads are ds_read_b128.
// B (regs): 8 per-lane fp32 query loads per K-step, cvt to bf16.
// acc0..3 = raw dots (4 N... M-tiles of 32 scols); accg = query patch Gram.
// ---------------------------------------------------------------------------
__global__ __launch_bounds__(256, 2) void k_fused(const float* __restrict__ base,
                                                  const float* __restrict__ query,
                                                  const float* __restrict__ invs,
                                                  const float* __restrict__ invsm,
                                                  const float* __restrict__ r,
                                                  float* __restrict__ out)
{
    __shared__ __align__(16) ushort s_lds[DG * ROWS * 8];   // 41280 B
    __shared__ float invs_l[WAY * HW];
    __shared__ float invsm_l[WAY];

    const int tid  = threadIdx.x;
    const int wid  = tid >> 6;
    const int lane = tid & 63;
    const int p    = lane & 31;        // query patch (col of C), 25 used
    const int hi   = lane >> 5;

    // XCD-chunked swizzle: each XCD gets 152 consecutive work ids -> 8 b's.
    const int wk = (blockIdx.x & 7) * (int)(gridDim.x >> 3) + (blockIdx.x >> 3);
    const int b  = wk / BPB;
    const int qb = wk - b * BPB;
    const int q  = qb * QPB + wid;
    const bool qok = q < NQ;

    if (tid < WAY * HW) invs_l[tid] = invs[b * WAY * HW + tid];
    if (tid < WAY)      invsm_l[tid] = invsm[b * WAY + tid];

    f32x16 acc0 = {}, acc1 = {}, acc2 = {}, acc3 = {}, accg = {};

    const int pc = (p < HW) ? p : (HW - 1);     // clamp pad lanes
    const float* qp = query + (size_t)(b * NQ + (qok ? q : 0)) * (DCH * HW) + pc;

    for (int c = 0; c < NCH; ++c) {
        __syncthreads();                         // prev chunk fully consumed
        // ---- stage support chunk (fp32 -> bf16, transposed to [dg][scol][8])
        for (int rr = tid; rr < WAY * KC; rr += 256) {
            const int k = rr / KC, dloc = rr - k * KC;
            const float* src = base + ((size_t)(b * WAY + k) * DCH + c * KC + dloc) * HW;
            ushort* dst = &s_lds[(((dloc >> 3) * ROWS) + k * HW) * 8 + (dloc & 7)];
            #pragma unroll
            for (int l = 0; l < HW; ++l) dst[l * 8] = f2bf(src[l]);
        }
        for (int i = tid; i < DG * 3; i += 256) {          // zero pad scols 125..127
            const int dg = i / 3, rz = 125 + (i - dg * 3);
            *(ulonglong2*)&s_lds[(dg * ROWS + rz) * 8] = ulonglong2{0ull, 0ull};
        }
        __syncthreads();

        if (qok) {
            #pragma unroll
            for (int st = 0; st < KC / 16; ++st) {
                const int dg = st * 2 + hi;
                // B fragment: q[d][p] for 8 consecutive d
                const float* qs = qp + (size_t)(c * KC + st * 16 + hi * 8) * HW;
                bf16x8 bq;
                #pragma unroll
                for (int e = 0; e < 8; ++e) bq[e] = (short)f2bf(qs[e * HW]);
                // A fragments: contiguous b128 reads
                const bf16x8* arow = (const bf16x8*)&s_lds[(dg * ROWS) * 8];
                bf16x8 a0 = arow[p];
                bf16x8 a1 = arow[32 + p];
                bf16x8 a2 = arow[64 + p];
                bf16x8 a3 = arow[96 + p];
                acc0 = __builtin_amdgcn_mfma_f32_32x32x16_bf16(a0, bq, acc0, 0, 0, 0);
                acc1 = __builtin_amdgcn_mfma_f32_32x32x16_bf16(a1, bq, acc1, 0, 0, 0);
                acc2 = __builtin_amdgcn_mfma_f32_32x32x16_bf16(a2, bq, acc2, 0, 0, 0);
                acc3 = __builtin_amdgcn_mfma_f32_32x32x16_bf16(a3, bq, acc3, 0, 0, 0);
                accg = __builtin_amdgcn_mfma_f32_32x32x16_bf16(bq, bq, accg, 0, 0, 0);
            }
        }
    }
    if (!qok) return;

    // ---- epilogue (wave-local, shfl only) ----
    // C/D layout (m74/m101): col = lane&31, row = (reg&3) + 8*(reg>>2) + 4*hi.
    const bool pok = p < HW;

    // 1/||q_p|| from Gram diagonal
    float diag = 0.f;
    #pragma unroll
    for (int rr = 0; rr < 16; ++rr) {
        const int rowb = (rr & 3) + 8 * (rr >> 2);
        diag = ((rowb + 4 * hi) == p) ? accg[rr] : diag;
    }
    diag += __shfl_xor(diag, 32);
    const float invq = rsqrtf(diag);

    // global-branch raw sums per way + Gram total (for ||qmean||)
    float gs[WAY] = {0.f, 0.f, 0.f, 0.f, 0.f};
    float qq = 0.f;
    #pragma unroll
    for (int rr = 0; rr < 16; ++rr) {
        const int rowb = (rr & 3) + 8 * (rr >> 2);
        const float v0 = hi ? 0.f : accg[rr];
        const float v1 = hi ? accg[rr] : 0.f;
        if (rowb < HW)     qq += v0;
        if (rowb + 4 < HW) qq += v1;
    }
#define TILE_SUM(ACC, T)                                            \
    _Pragma("unroll")                                               \
    for (int rr = 0; rr < 16; ++rr) {                               \
        const int s0 = (T) * 32 + (rr & 3) + 8 * (rr >> 2);         \
        const float v0 = hi ? 0.f : ACC[rr];                        \
        const float v1 = hi ? ACC[rr] : 0.f;                        \
        if (s0 < 125)     gs[s0 / 25]       += v0;                  \
        if (s0 + 4 < 125) gs[(s0 + 4) / 25] += v1;                  \
    }
    TILE_SUM(acc0, 0) TILE_SUM(acc1, 1) TILE_SUM(acc2, 2) TILE_SUM(acc3, 3)
#undef TILE_SUM

    if (!pok) {
        qq = 0.f;
        #pragma unroll
        for (int g = 0; g < WAY; ++g) gs[g] = 0.f;
    }
    #pragma unroll
    for (int o = 1; o < 64; o <<= 1) {
        qq += __shfl_xor(qq, o);
        #pragma unroll
        for (int g = 0; g < WAY; ++g) gs[g] += __shfl_xor(gs[g], o);
    }

    // flatten tiles for static gather
    float A[64];
    #pragma unroll
    for (int rr = 0; rr < 16; ++rr) {
        A[rr] = acc0[rr]; A[16 + rr] = acc1[rr]; A[32 + rr] = acc2[rr]; A[48 + rr] = acc3[rr];
    }

    // DN4: per way, gather the 25 scaled sims for this lane's patch, top-5
    float tots[WAY];
    #pragma unroll
    for (int g = 0; g < WAY; ++g) {
        float v[HW];
        #pragma unroll
        for (int j = 0; j < HW; ++j) {
            const int scol = g * HW + j;
            const int t = scol >> 5, row = scol & 31;
            const int hreq = (row >> 2) & 1;
            const int rr = (row & 3) | ((row >> 3) << 2);
            float mine = (hi == hreq) ? A[t * 16 + rr] : 0.f;
            mine += __shfl_xor(mine, 32);
            v[j] = mine * invq * invs_l[scol];
        }
        float gtot = 0.f;
        #pragma unroll
        for (int it = 0; it < NBK; ++it) {
            float m = v[0];
            #pragma unroll
            for (int j = 1; j < HW; ++j) m = fmaxf(m, v[j]);
            gtot += m;
            bool rem = false;
            #pragma unroll
            for (int j = 0; j < HW; ++j) {
                const bool hit = (!rem) && (v[j] == m);
                v[j] = hit ? -3.402823466e38f : v[j];
                rem = rem || hit;
            }
        }
        tots[g] = pok ? gtot : 0.f;
    }
    #pragma unroll
    for (int o = 1; o < 64; o <<= 1) {
        #pragma unroll
        for (int g = 0; g < WAY; ++g) tots[g] += __shfl_xor(tots[g], o);
    }

    const float r0 = r[0], r1 = r[1];
    const float invqm = 1.0f / fmaxf(sqrtf(qq) * (1.0f / HW), EPSN);  // 1/max(||qmean||,eps)
    float res[WAY];
    #pragma unroll
    for (int g = 0; g < WAY; ++g)
        res[g] = r0 * gs[g] * (1.0f / 625.0f) * invqm * invsm_l[g]
               + r1 * tots[g] * 0.5f * (1.0f / NBK);   // 0.5: hi-halves duplicate

    float ov = res[0];
    ov = (lane == 1) ? res[1] : ov;
    ov = (lane == 2) ? res[2] : ov;
    ov = (lane == 3) ? res[3] : ov;
    ov = (lane == 4) ? res[4] : ov;
    if (lane < WAY) out[(size_t)(b * NQ + q) * WAY + lane] = ov;
}

// ---------------------------------------------------------------------------
extern "C" void kernel_launch(void* const* d_in, const int* in_sizes, int n_in,
                              void* d_out, int out_size, void* d_ws, size_t ws_size,
                              hipStream_t stream)
{
    const float* base  = (const float*)d_in[0];
    const float* query = (const float*)d_in[1];
    const float* r     = (const float*)d_in[2];
    float* out = (float*)d_out;

    float* invs  = (float*)d_ws;                 // 320*25 floats
    float* invsm = invs + NB * WAY * HW;         // 320 floats

    k_prep<<<NB * WAY, 256, 0, stream>>>(base, invs, invsm);
    k_fused<<<NB * BPB, 256, 0, stream>>>(base, query, invs, invsm, r, out);
}